// Round 3
// baseline (102.636 us; speedup 1.0000x reference)
//
#include <hip/hip_runtime.h>
#include <math.h>

#define BATCH 16
#define N_ROIS 1000
#define NUM_CLASSES 81
#define DET_MAX 100
#define MIN_CONF 0.7f
#define NMS_THRESH 0.3f

#define TILE_ROIS 200              // 200*81*4 B = 64.8 KB tile; 5 tiles/batch
#define N_TILES (N_ROIS / TILE_ROIS)
#define TILE_F4 (TILE_ROIS * NUM_CLASSES / 4)   // 4050 float4 per tile
#define BLOCK 1024

// One block per batch image. Phase 1: stream probs through LDS tiles
// (float4-coalesced), per-ROI argmax + refine + clip, compact candidates
// (score >= MIN_CONF, class > 0) straight into LDS. Phase 2: rank-sort by
// (score desc, roi-idx asc), single greedy walk with lane-parallel same-class
// suppression and per-class DET_MAX cap, emit in kept order (== lax.top_k
// order). Semantics identical to the R2 pair (absmax 0.0), minus the global
// workspace round-trip and the second launch.
__global__ __launch_bounds__(BLOCK) void detection_fused(
    const float* __restrict__ rois, const float* __restrict__ probs,
    const float* __restrict__ deltas, const float* __restrict__ window,
    float* __restrict__ out)
{
    const int b = blockIdx.x;
    const int tid = threadIdx.x;

    __shared__ float s_tile[TILE_ROIS * NUM_CLASSES];   // 64.8 KB
    __shared__ float s_cbox[N_ROIS][4];                 // 16 KB  candidates
    __shared__ float s_csc[N_ROIS];                     //  4 KB
    __shared__ short s_cidx[N_ROIS];                    //  2 KB  roi idx (tie-break)
    __shared__ unsigned char s_ccls[N_ROIS];            //  1 KB
    __shared__ float s_sbox[N_ROIS][4];                 // 16 KB  sorted
    __shared__ float s_ssc[N_ROIS];                     //  4 KB
    __shared__ unsigned char s_scls[N_ROIS];            //  1 KB
    __shared__ unsigned char s_supp[N_ROIS];            //  1 KB
    __shared__ unsigned char s_kept[N_ROIS];            //  1 KB
    __shared__ short s_slot[N_ROIS];                    //  2 KB
    __shared__ int s_cnt[NUM_CLASSES];
    __shared__ int s_C;

    if (tid == 0) s_C = 0;
    if (tid < NUM_CLASSES) s_cnt[tid] = 0;

    // zero this batch's output rows (d_out is poisoned before every replay)
    for (int i = tid; i < DET_MAX * 6; i += BLOCK)
        out[(size_t)b * DET_MAX * 6 + i] = 0.0f;

    const float* win = window + b * 4;   // uniform loads
    const float wy1 = win[0], wx1 = win[1], wy2 = win[2], wx2 = win[3];

    const float4* pbase = (const float4*)(probs + (size_t)b * N_ROIS * NUM_CLASSES);

    // ---------------- Phase 1: refine + compact ----------------
    for (int t = 0; t < N_TILES; ++t) {
        const float4* src = pbase + (size_t)t * TILE_F4;
        float4* dst = (float4*)s_tile;
        for (int i = tid; i < TILE_F4; i += BLOCK)
            dst[i] = src[i];
        __syncthreads();

        if (tid < TILE_ROIS) {
            const int r = t * TILE_ROIS + tid;          // roi within batch
            // argmax over 81 class probs (first max wins == jnp.argmax);
            // LDS row stride 81 floats -> bank stride 17 (odd): 2-way only, free
            const float* p = s_tile + tid * NUM_CLASSES;
            int best = 0;
            float bs = p[0];
            for (int c = 1; c < NUM_CLASSES; ++c) {
                float v = p[c];
                if (v > bs) { bs = v; best = c; }
            }

            if (best > 0 && bs >= MIN_CONF) {
                const int gidx = b * N_ROIS + r;
                const float4 dd = ((const float4*)deltas)[(size_t)gidx * NUM_CLASSES + best];
                float dy = dd.x * 0.1f, dx = dd.y * 0.1f, dh = dd.z * 0.2f, dw = dd.w * 0.2f;

                const float4 rr = ((const float4*)rois)[gidx];
                float y1 = rr.x, x1 = rr.y, y2 = rr.z, x2 = rr.w;
                float h = y2 - y1, w = x2 - x1;
                float cy = y1 + 0.5f * h, cx = x1 + 0.5f * w;
                cy += dy * h;
                cx += dx * w;
                h *= expf(dh);
                w *= expf(dw);
                float ny1 = cy - 0.5f * h;
                float nx1 = cx - 0.5f * w;
                float ny2 = ny1 + h;   // matches reference: y2 = y1 + h
                float nx2 = nx1 + w;

                ny1 = fminf(fmaxf(ny1, wy1), wy2);
                nx1 = fminf(fmaxf(nx1, wx1), wx2);
                ny2 = fminf(fmaxf(ny2, wy1), wy2);
                nx2 = fminf(fmaxf(nx2, wx1), wx2);

                int k = atomicAdd(&s_C, 1);   // order irrelevant: rank-scatter below
                s_cbox[k][0] = ny1; s_cbox[k][1] = nx1;
                s_cbox[k][2] = ny2; s_cbox[k][3] = nx2;
                s_csc[k] = bs;
                s_cidx[k] = (short)r;
                s_ccls[k] = (unsigned char)best;
            }
        }
        __syncthreads();   // s_tile reused next iteration
    }
    const int C = s_C;

    // ---------------- Phase 2a: rank-sort by (score desc, idx asc) ----------------
    for (int k = tid; k < C; k += BLOCK) {
        float sk = s_csc[k];
        int ik = s_cidx[k];
        int rank = 0;
        for (int j = 0; j < C; ++j) {   // broadcast LDS reads
            float sj = s_csc[j];
            rank += (sj > sk) | ((sj == sk) & (s_cidx[j] < ik));
        }
        s_ssc[rank] = sk;
        s_scls[rank] = s_ccls[k];
        s_sbox[rank][0] = s_cbox[k][0];
        s_sbox[rank][1] = s_cbox[k][1];
        s_sbox[rank][2] = s_cbox[k][2];
        s_sbox[rank][3] = s_cbox[k][3];
        s_supp[rank] = 0;
        s_kept[rank] = 0;
        s_slot[rank] = 0;
    }
    __syncthreads();

    // ---------------- Phase 2b: serial greedy walk (wave 0) ----------------
    // per-class greedy NMS in global (score desc, idx asc) order; a kept box
    // suppresses only same-class later boxes; capped classes neither keep nor
    // suppress; kept order == top_k output order; first 100 kept suffice.
    if (tid < 64) {
        int total = 0;
        for (int i = 0; i < C; ++i) {
            if (s_supp[i]) continue;               // wave-uniform broadcast
            int c = s_scls[i];
            int cn = s_cnt[c];
            if (cn >= DET_MAX) continue;
            s_cnt[c] = cn + 1;                     // all lanes write same value
            if (tid == 0) { s_kept[i] = 1; s_slot[i] = (short)total; }
            ++total;
            float a0 = s_sbox[i][0], a1 = s_sbox[i][1];
            float a2 = s_sbox[i][2], a3 = s_sbox[i][3];
            float area_a = (a2 - a0) * (a3 - a1);
            for (int j = i + 1 + tid; j < C; j += 64) {
                if (s_supp[j] || s_scls[j] != c) continue;
                float b0 = s_sbox[j][0], b1 = s_sbox[j][1];
                float b2 = s_sbox[j][2], b3 = s_sbox[j][3];
                float yy1 = fmaxf(a0, b0);
                float xx1 = fmaxf(a1, b1);
                float yy2 = fminf(a2, b2);
                float xx2 = fminf(a3, b3);
                float inter = fmaxf(yy2 - yy1, 0.0f) * fmaxf(xx2 - xx1, 0.0f);
                float area_b = (b2 - b0) * (b3 - b1);
                float uni = area_a + area_b - inter;
                if (inter / fmaxf(uni, 1e-10f) > NMS_THRESH) s_supp[j] = 1;
            }
            if (total == DET_MAX) break;
        }
    }
    __syncthreads();

    // ---------------- Phase 2c: emit ----------------
    for (int i = tid; i < C; i += BLOCK) {
        if (s_kept[i]) {
            float* o = out + (size_t)b * DET_MAX * 6 + s_slot[i] * 6;
            o[0] = s_sbox[i][0];
            o[1] = s_sbox[i][1];
            o[2] = s_sbox[i][2];
            o[3] = s_sbox[i][3];
            o[4] = (float)s_scls[i];
            o[5] = s_ssc[i];
        }
    }
}

extern "C" void kernel_launch(void* const* d_in, const int* in_sizes, int n_in,
                              void* d_out, int out_size, void* d_ws, size_t ws_size,
                              hipStream_t stream) {
    const float* rois      = (const float*)d_in[0];
    const float* fpn_class = (const float*)d_in[1];
    const float* fpn_bbox  = (const float*)d_in[2];
    const float* window    = (const float*)d_in[3];
    float* out = (float*)d_out;

    detection_fused<<<BATCH, BLOCK, 0, stream>>>(
        rois, fpn_class, fpn_bbox, window, out);
}

// Round 4
// 88.448 us; speedup vs baseline: 1.1604x; 1.1604x over previous
//
#include <hip/hip_runtime.h>
#include <math.h>

#define BATCH 16
#define N_ROIS 1000
#define NUM_CLASSES 81
#define DET_MAX 100
#define MIN_CONF 0.7f
#define NMS_THRESH 0.3f

#define ROI_TILE 128          // ROIs per block in refine kernel

// ---------------- Kernel A: per-ROI argmax + box refine + clip ----------------
// 125 blocks (max parallelism for the probs stream). Boxes/cls are written
// ONLY for candidates (keep==true); non-candidate refined boxes are never
// read downstream (NMS uses only score>=0 entries; top_k rows for non-kept
// indices are zeroed by the valid mask), so skipping them is exact.
__global__ __launch_bounds__(256) void refine_v3(
    const float* __restrict__ rois, const float* __restrict__ probs,
    const float* __restrict__ deltas, const float* __restrict__ window,
    float* __restrict__ ws_box, float* __restrict__ ws_score, int* __restrict__ ws_cls)
{
    __shared__ float s_probs[ROI_TILE * NUM_CLASSES];   // 40.5 KB

    const int base_roi = blockIdx.x * ROI_TILE;

    // coalesced float4 staging: 128*81/4 = 2592 float4; base byte offset
    // base_roi*324 divisible by 16 since base_roi % 4 == 0.
    const float4* src = (const float4*)(probs + (size_t)base_roi * NUM_CLASSES);
    float4* dst = (float4*)s_probs;
    for (int i = threadIdx.x; i < ROI_TILE * NUM_CLASSES / 4; i += 256)
        dst[i] = src[i];
    __syncthreads();

    if (threadIdx.x < ROI_TILE) {
        const int idx = base_roi + threadIdx.x;   // flat ROI id, < 16000
        const int b = idx / N_ROIS;

        // argmax over 81 class probs (first max wins, matching jnp.argmax);
        // LDS row stride 81 floats -> odd bank stride: at most 2-way (free)
        const float* p = s_probs + threadIdx.x * NUM_CLASSES;
        int best = 0;
        float bs = p[0];
        for (int c = 1; c < NUM_CLASSES; ++c) {
            float v = p[c];
            if (v > bs) { bs = v; best = c; }
        }

        const bool keep = (best > 0) && (bs >= MIN_CONF);
        ws_score[idx] = keep ? bs : -1.0f;

        if (keep) {
            const float4 dd = ((const float4*)deltas)[(size_t)idx * NUM_CLASSES + best];
            float dy = dd.x * 0.1f, dx = dd.y * 0.1f, dh = dd.z * 0.2f, dw = dd.w * 0.2f;

            const float4 rr = ((const float4*)rois)[idx];
            float y1 = rr.x, x1 = rr.y, y2 = rr.z, x2 = rr.w;
            float h = y2 - y1, w = x2 - x1;
            float cy = y1 + 0.5f * h, cx = x1 + 0.5f * w;
            cy += dy * h;
            cx += dx * w;
            h *= expf(dh);
            w *= expf(dw);
            float ny1 = cy - 0.5f * h;
            float nx1 = cx - 0.5f * w;
            float ny2 = ny1 + h;   // matches reference: y2 = y1 + h
            float nx2 = nx1 + w;

            const float* win = window + b * 4;
            float wy1 = win[0], wx1 = win[1], wy2 = win[2], wx2 = win[3];
            ny1 = fminf(fmaxf(ny1, wy1), wy2);
            nx1 = fminf(fmaxf(nx1, wx1), wx2);
            ny2 = fminf(fmaxf(ny2, wy1), wy2);
            nx2 = fminf(fmaxf(nx2, wx1), wx2);

            ((float4*)ws_box)[idx] = make_float4(ny1, nx1, ny2, nx2);
            ws_cls[idx] = best;
        }
    }
}

// ---------------- Kernel B: per-batch sort + per-class parallel NMS + top-K ----
// Equivalence to the reference:
//  - global rank-sort by (score desc, roi-idx asc) preserves each class's
//    stable argsort(-sc) order, so per-class greedy NMS over the class's
//    bucket (in sorted order) is exactly the reference recursion: a box is
//    kept iff not suppressed by an earlier KEPT same-class box, with the
//    DET_MAX cap (capped boxes neither keep nor suppress downstream output).
//  - kept subset enumerated in global sorted order == lax.top_k order of sf;
//    slot = prefix count of kept flags; slots >= 100 dropped, rest zeroed.
__global__ __launch_bounds__(256) void nms_v3(
    const float* __restrict__ ws_box, const float* __restrict__ ws_score,
    const int* __restrict__ ws_cls, float* __restrict__ out)
{
    const int b = blockIdx.x;
    const int tid = threadIdx.x;

    __shared__ float s_cbox[N_ROIS][4];        // candidates (compaction order)
    __shared__ float s_csc[N_ROIS];
    __shared__ short s_cidx[N_ROIS];           // original roi idx (tie-break)
    __shared__ unsigned char s_ccls[N_ROIS];
    __shared__ float s_sbox[N_ROIS][4];        // sorted
    __shared__ float s_ssc[N_ROIS];
    __shared__ unsigned char s_scls[N_ROIS];
    __shared__ unsigned char s_kept[N_ROIS];
    __shared__ short s_bucket[N_ROIS];         // per-class lists of sorted idx
    __shared__ int s_cnt[NUM_CLASSES];
    __shared__ int s_off[NUM_CLASSES];
    __shared__ int s_C;

    if (tid == 0) s_C = 0;
    if (tid < NUM_CLASSES) s_cnt[tid] = 0;

    // zero this batch's output rows (d_out is poisoned before every replay)
    for (int i = tid; i < DET_MAX * 6; i += 256)
        out[(size_t)b * DET_MAX * 6 + i] = 0.0f;
    __syncthreads();

    // ---- compact candidates (score >= 0) into LDS ----
    for (int i = tid; i < N_ROIS; i += 256) {
        float sc = ws_score[b * N_ROIS + i];
        if (sc >= 0.0f) {
            int k = atomicAdd(&s_C, 1);
            s_csc[k] = sc;
            s_cidx[k] = (short)i;
            int c = ws_cls[b * N_ROIS + i];
            s_ccls[k] = (unsigned char)c;
            atomicAdd(&s_cnt[c], 1);
            float4 bb = ((const float4*)ws_box)[b * N_ROIS + i];
            s_cbox[k][0] = bb.x; s_cbox[k][1] = bb.y;
            s_cbox[k][2] = bb.z; s_cbox[k][3] = bb.w;
        }
    }
    __syncthreads();
    const int C = s_C;

    // ---- rank-sort by (score desc, idx asc): strict total order ----
    for (int k = tid; k < C; k += 256) {
        float sk = s_csc[k];
        int ik = s_cidx[k];
        int rank = 0;
        for (int j = 0; j < C; ++j) {   // broadcast LDS reads
            float sj = s_csc[j];
            rank += (sj > sk) | ((sj == sk) & (s_cidx[j] < ik));
        }
        s_ssc[rank] = sk;
        s_scls[rank] = s_ccls[k];
        s_sbox[rank][0] = s_cbox[k][0];
        s_sbox[rank][1] = s_cbox[k][1];
        s_sbox[rank][2] = s_cbox[k][2];
        s_sbox[rank][3] = s_cbox[k][3];
        s_kept[rank] = 0;
    }
    if (tid == 0) {      // class bucket offsets (81 adds, trivial)
        int acc = 0;
        for (int c = 0; c < NUM_CLASSES; ++c) { s_off[c] = acc; acc += s_cnt[c]; }
    }
    __syncthreads();

    // ---- build per-class bucket lists in sorted order ----
    // thread c scans the sorted list (broadcast reads) and appends its own.
    if (tid >= 1 && tid < NUM_CLASSES) {
        int p = s_off[tid];
        for (int i = 0; i < C; ++i)
            if (s_scls[i] == tid) s_bucket[p++] = (short)i;
    }
    __syncthreads();

    // ---- per-class greedy NMS, all classes in parallel ----
    if (tid >= 1 && tid < NUM_CLASSES) {
        const int off = s_off[tid];
        const int m = s_cnt[tid];
        int kept_cnt = 0;
        for (int a = 0; a < m; ++a) {
            if (kept_cnt >= DET_MAX) break;    // capped: never kept, never used
            int i = s_bucket[off + a];
            float b0 = s_sbox[i][0], b1 = s_sbox[i][1];
            float b2 = s_sbox[i][2], b3 = s_sbox[i][3];
            float area_b = (b2 - b0) * (b3 - b1);
            bool sup = false;
            for (int q = 0; q < a; ++q) {
                int j = s_bucket[off + q];
                if (!s_kept[j]) continue;      // only KEPT boxes suppress
                float a0 = s_sbox[j][0], a1 = s_sbox[j][1];
                float a2 = s_sbox[j][2], a3 = s_sbox[j][3];
                float yy1 = fmaxf(a0, b0);
                float xx1 = fmaxf(a1, b1);
                float yy2 = fminf(a2, b2);
                float xx2 = fminf(a3, b3);
                float inter = fmaxf(yy2 - yy1, 0.0f) * fmaxf(xx2 - xx1, 0.0f);
                float area_a = (a2 - a0) * (a3 - a1);
                float uni = area_a + area_b - inter;
                if (inter / fmaxf(uni, 1e-10f) > NMS_THRESH) { sup = true; break; }
            }
            if (!sup) { s_kept[i] = 1; ++kept_cnt; }
        }
    }
    __syncthreads();

    // ---- emit: slot = prefix count of kept in sorted order (== top_k order) ----
    for (int i = tid; i < C; i += 256) {
        if (s_kept[i]) {
            int slot = 0;
            for (int j = 0; j < i; ++j) slot += s_kept[j];
            if (slot < DET_MAX) {
                float* o = out + (size_t)b * DET_MAX * 6 + slot * 6;
                o[0] = s_sbox[i][0];
                o[1] = s_sbox[i][1];
                o[2] = s_sbox[i][2];
                o[3] = s_sbox[i][3];
                o[4] = (float)s_scls[i];
                o[5] = s_ssc[i];
            }
        }
    }
}

extern "C" void kernel_launch(void* const* d_in, const int* in_sizes, int n_in,
                              void* d_out, int out_size, void* d_ws, size_t ws_size,
                              hipStream_t stream) {
    const float* rois      = (const float*)d_in[0];
    const float* fpn_class = (const float*)d_in[1];
    const float* fpn_bbox  = (const float*)d_in[2];
    const float* window    = (const float*)d_in[3];
    float* out = (float*)d_out;

    // workspace layout: boxes | scores | class ids  (384 KB of d_ws)
    float* ws_box   = (float*)d_ws;                        // BATCH*N_ROIS*4
    float* ws_score = ws_box + (size_t)BATCH * N_ROIS * 4; // BATCH*N_ROIS
    int*   ws_cls   = (int*)(ws_score + (size_t)BATCH * N_ROIS);

    refine_v3<<<BATCH * N_ROIS / ROI_TILE, 256, 0, stream>>>(
        rois, fpn_class, fpn_bbox, window, ws_box, ws_score, ws_cls);
    nms_v3<<<BATCH, 256, 0, stream>>>(ws_box, ws_score, ws_cls, out);
}

// Round 5
// 85.502 us; speedup vs baseline: 1.2004x; 1.0345x over previous
//
#include <hip/hip_runtime.h>
#include <math.h>

#define BATCH 16
#define N_ROIS 1000
#define NUM_CLASSES 81
#define DET_MAX 100
#define MIN_CONF 0.7f
#define NMS_THRESH 0.3f

#define ROI_TILE 128          // ROIs per block in refine kernel

// ---------------- Kernel A: per-ROI argmax + box refine + clip ----------------
// 125 blocks. Argmax done as 4 independent chains (dep depth 80 -> ~20) merged
// with index tie-breaks: picks the lowest-index maximum == jnp.argmax.
__global__ __launch_bounds__(256) void refine_v4(
    const float* __restrict__ rois, const float* __restrict__ probs,
    const float* __restrict__ deltas, const float* __restrict__ window,
    float* __restrict__ ws_box, float* __restrict__ ws_score, int* __restrict__ ws_cls)
{
    __shared__ float s_probs[ROI_TILE * NUM_CLASSES];   // 40.5 KB

    const int base_roi = blockIdx.x * ROI_TILE;

    // coalesced float4 staging: 128*81/4 = 2592 float4 (base 16B-aligned)
    const float4* src = (const float4*)(probs + (size_t)base_roi * NUM_CLASSES);
    float4* dst = (float4*)s_probs;
    for (int i = threadIdx.x; i < ROI_TILE * NUM_CLASSES / 4; i += 256)
        dst[i] = src[i];
    __syncthreads();

    if (threadIdx.x < ROI_TILE) {
        const int idx = base_roi + threadIdx.x;   // flat ROI id, < 16000
        const int b = idx / N_ROIS;

        // 4-chain argmax over 81 probs; within-chain: strict > keeps first max;
        // cross-chain merge: (s_b > s_a) || (s_b == s_a && i_b < i_a) keeps the
        // lowest-index maximum at every merge => global first-max (jnp.argmax).
        const float* p = s_probs + threadIdx.x * NUM_CLASSES;
        float bs0 = p[0], bs1 = p[1], bs2 = p[2], bs3 = p[3];
        int ib0 = 0, ib1 = 1, ib2 = 2, ib3 = 3;
        #pragma unroll
        for (int c = 4; c <= 76; c += 4) {
            float v0 = p[c], v1 = p[c + 1], v2 = p[c + 2], v3 = p[c + 3];
            if (v0 > bs0) { bs0 = v0; ib0 = c; }
            if (v1 > bs1) { bs1 = v1; ib1 = c + 1; }
            if (v2 > bs2) { bs2 = v2; ib2 = c + 2; }
            if (v3 > bs3) { bs3 = v3; ib3 = c + 3; }
        }
        { float v = p[80]; if (v > bs0) { bs0 = v; ib0 = 80; } }
        // merges (lowest index wins ties)
        if (bs1 > bs0 || (bs1 == bs0 && ib1 < ib0)) { bs0 = bs1; ib0 = ib1; }
        if (bs3 > bs2 || (bs3 == bs2 && ib3 < ib2)) { bs2 = bs3; ib2 = ib3; }
        if (bs2 > bs0 || (bs2 == bs0 && ib2 < ib0)) { bs0 = bs2; ib0 = ib2; }
        const float bs = bs0;
        const int best = ib0;

        const bool keep = (best > 0) && (bs >= MIN_CONF);
        ws_score[idx] = keep ? bs : -1.0f;

        if (keep) {
            const float4 dd = ((const float4*)deltas)[(size_t)idx * NUM_CLASSES + best];
            float dy = dd.x * 0.1f, dx = dd.y * 0.1f, dh = dd.z * 0.2f, dw = dd.w * 0.2f;

            const float4 rr = ((const float4*)rois)[idx];
            float y1 = rr.x, x1 = rr.y, y2 = rr.z, x2 = rr.w;
            float h = y2 - y1, w = x2 - x1;
            float cy = y1 + 0.5f * h, cx = x1 + 0.5f * w;
            cy += dy * h;
            cx += dx * w;
            h *= expf(dh);
            w *= expf(dw);
            float ny1 = cy - 0.5f * h;
            float nx1 = cx - 0.5f * w;
            float ny2 = ny1 + h;   // matches reference: y2 = y1 + h
            float nx2 = nx1 + w;

            const float* win = window + b * 4;
            float wy1 = win[0], wx1 = win[1], wy2 = win[2], wx2 = win[3];
            ny1 = fminf(fmaxf(ny1, wy1), wy2);
            nx1 = fminf(fmaxf(nx1, wx1), wx2);
            ny2 = fminf(fmaxf(ny2, wy1), wy2);
            nx2 = fminf(fmaxf(nx2, wx1), wx2);

            ((float4*)ws_box)[idx] = make_float4(ny1, nx1, ny2, nx2);
            ws_cls[idx] = best;
        }
    }
}

// ---------------- Kernel B: per-batch sort + per-class parallel NMS + top-K ----
// Same semantics as R4 (absmax 0.0). New: class-rank computed inside the main
// rank loop, so class buckets are scattered in parallel (no serial per-class
// scan over the sorted list).
__global__ __launch_bounds__(256) void nms_v4(
    const float* __restrict__ ws_box, const float* __restrict__ ws_score,
    const int* __restrict__ ws_cls, float* __restrict__ out)
{
    const int b = blockIdx.x;
    const int tid = threadIdx.x;

    __shared__ float s_cbox[N_ROIS][4];        // candidates (compaction order)
    __shared__ float s_csc[N_ROIS];
    __shared__ short s_cidx[N_ROIS];           // original roi idx (tie-break)
    __shared__ unsigned char s_ccls[N_ROIS];
    __shared__ float s_sbox[N_ROIS][4];        // sorted by (score desc, idx asc)
    __shared__ float s_ssc[N_ROIS];
    __shared__ unsigned char s_scls[N_ROIS];
    __shared__ unsigned char s_kept[N_ROIS];
    __shared__ short s_bucket[N_ROIS];         // per-class lists of sorted idx
    __shared__ int s_cnt[NUM_CLASSES];
    __shared__ int s_off[NUM_CLASSES];
    __shared__ int s_C;

    if (tid == 0) s_C = 0;
    if (tid < NUM_CLASSES) s_cnt[tid] = 0;

    // zero this batch's output rows (d_out is poisoned before every replay)
    for (int i = tid; i < DET_MAX * 6; i += 256)
        out[(size_t)b * DET_MAX * 6 + i] = 0.0f;
    __syncthreads();

    // ---- compact candidates (score >= 0) into LDS ----
    for (int i = tid; i < N_ROIS; i += 256) {
        float sc = ws_score[b * N_ROIS + i];
        if (sc >= 0.0f) {
            int k = atomicAdd(&s_C, 1);
            s_csc[k] = sc;
            s_cidx[k] = (short)i;
            int c = ws_cls[b * N_ROIS + i];
            s_ccls[k] = (unsigned char)c;
            atomicAdd(&s_cnt[c], 1);
            float4 bb = ((const float4*)ws_box)[b * N_ROIS + i];
            s_cbox[k][0] = bb.x; s_cbox[k][1] = bb.y;
            s_cbox[k][2] = bb.z; s_cbox[k][3] = bb.w;
        }
    }
    __syncthreads();
    const int C = s_C;

    if (tid == 0) {      // class bucket offsets (pipelined LDS reads, trivial)
        int acc = 0;
        for (int c = 0; c < NUM_CLASSES; ++c) { s_off[c] = acc; acc += s_cnt[c]; }
    }
    __syncthreads();

    // ---- rank-sort by (score desc, idx asc) + direct class-bucket scatter ----
    // (sc, idx) is a strict total order; rank is global position, crank is
    // position within this candidate's class (same order restricted to class).
    for (int k = tid; k < C; k += 256) {
        float sk = s_csc[k];
        int ik = s_cidx[k];
        int ck = s_ccls[k];
        int rank = 0, crank = 0;
        for (int j = 0; j < C; ++j) {   // broadcast LDS reads
            float sj = s_csc[j];
            int before = (sj > sk) | ((sj == sk) & (s_cidx[j] < ik));
            rank += before;
            crank += before & (s_ccls[j] == ck);
        }
        s_ssc[rank] = sk;
        s_scls[rank] = (unsigned char)ck;
        s_sbox[rank][0] = s_cbox[k][0];
        s_sbox[rank][1] = s_cbox[k][1];
        s_sbox[rank][2] = s_cbox[k][2];
        s_sbox[rank][3] = s_cbox[k][3];
        s_kept[rank] = 0;
        s_bucket[s_off[ck] + crank] = (short)rank;
    }
    __syncthreads();

    // ---- per-class greedy NMS, all classes in parallel ----
    // kept iff not suppressed (IoU > thresh) by an earlier KEPT same-class box;
    // per-class DET_MAX cap: capped boxes neither kept nor suppress output.
    if (tid >= 1 && tid < NUM_CLASSES) {
        const int off = s_off[tid];
        const int m = s_cnt[tid];
        int kept_cnt = 0;
        for (int a = 0; a < m; ++a) {
            if (kept_cnt >= DET_MAX) break;
            int i = s_bucket[off + a];
            float b0 = s_sbox[i][0], b1 = s_sbox[i][1];
            float b2 = s_sbox[i][2], b3 = s_sbox[i][3];
            float area_b = (b2 - b0) * (b3 - b1);
            bool sup = false;
            for (int q = 0; q < a; ++q) {
                int j = s_bucket[off + q];
                if (!s_kept[j]) continue;
                float a0 = s_sbox[j][0], a1 = s_sbox[j][1];
                float a2 = s_sbox[j][2], a3 = s_sbox[j][3];
                float yy1 = fmaxf(a0, b0);
                float xx1 = fmaxf(a1, b1);
                float yy2 = fminf(a2, b2);
                float xx2 = fminf(a3, b3);
                float inter = fmaxf(yy2 - yy1, 0.0f) * fmaxf(xx2 - xx1, 0.0f);
                float area_a = (a2 - a0) * (a3 - a1);
                float uni = area_a + area_b - inter;
                if (inter / fmaxf(uni, 1e-10f) > NMS_THRESH) { sup = true; break; }
            }
            if (!sup) { s_kept[i] = 1; ++kept_cnt; }
        }
    }
    __syncthreads();

    // ---- emit: slot = prefix count of kept in sorted order (== top_k order) ----
    for (int i = tid; i < C; i += 256) {
        if (s_kept[i]) {
            int slot = 0;
            for (int j = 0; j < i; ++j) slot += s_kept[j];   // independent reads, pipelined
            if (slot < DET_MAX) {
                float* o = out + (size_t)b * DET_MAX * 6 + slot * 6;
                o[0] = s_sbox[i][0];
                o[1] = s_sbox[i][1];
                o[2] = s_sbox[i][2];
                o[3] = s_sbox[i][3];
                o[4] = (float)s_scls[i];
                o[5] = s_ssc[i];
            }
        }
    }
}

extern "C" void kernel_launch(void* const* d_in, const int* in_sizes, int n_in,
                              void* d_out, int out_size, void* d_ws, size_t ws_size,
                              hipStream_t stream) {
    const float* rois      = (const float*)d_in[0];
    const float* fpn_class = (const float*)d_in[1];
    const float* fpn_bbox  = (const float*)d_in[2];
    const float* window    = (const float*)d_in[3];
    float* out = (float*)d_out;

    // workspace layout: boxes | scores | class ids  (384 KB of d_ws)
    float* ws_box   = (float*)d_ws;                        // BATCH*N_ROIS*4
    float* ws_score = ws_box + (size_t)BATCH * N_ROIS * 4; // BATCH*N_ROIS
    int*   ws_cls   = (int*)(ws_score + (size_t)BATCH * N_ROIS);

    refine_v4<<<BATCH * N_ROIS / ROI_TILE, 256, 0, stream>>>(
        rois, fpn_class, fpn_bbox, window, ws_box, ws_score, ws_cls);
    nms_v4<<<BATCH, 256, 0, stream>>>(ws_box, ws_score, ws_cls, out);
}